// Round 8
// baseline (617.770 us; speedup 1.0000x reference)
//
#include <hip/hip_runtime.h>
#include <math.h>

// Problem constants (B=10240, D=512, M=8, L=3)
#define BB   10240
#define DD   512
#define MM   8

typedef _Float16 h8 __attribute__((ext_vector_type(8)));
typedef float    f4 __attribute__((ext_vector_type(4)));

// ---------------- fp32 -> fp16 convert (8 elems/thread) ----------------
__global__ void __launch_bounds__(256) cvt_f32_f16(const float* __restrict__ s,
                                                   _Float16* __restrict__ d, int n8) {
    int i = blockIdx.x * 256 + threadIdx.x;
    if (i >= n8) return;
    const float4* sp = (const float4*)s + (size_t)i * 2;
    float4 a = sp[0], b = sp[1];
    h8 o = { (_Float16)a.x, (_Float16)a.y, (_Float16)a.z, (_Float16)a.w,
             (_Float16)b.x, (_Float16)b.y, (_Float16)b.z, (_Float16)b.w };
    *(h8*)(d + (size_t)i * 8) = o;
}

// ---------------- fused layer GEMM ----------------
// C[b,i] = gW[b,i] * sum_m pW[b,m] sum_j W[m,i,j] x[b,j]  +  gb[b,i]*sum_m pb[b,m]*bs[m,i]
//
// BARRIER-FREE register pipeline (R5 post-mortem: 2-barrier-per-step LDS
// structure was latency-bound at ~2500 cyc/step; counted vmcnt couldn't fix
// the rendezvous+LDS-round-trip critical path).  No LDS, no barriers, no
// manual waitcnt:
//  - W MFMA B-fragments loaded per-wave direct global->VGPR, 4 rotating
//    register sets, issued 2 m-steps ahead of use (compiler emits exact
//    counted vmcnt for VGPR-dest loads).  W slice is L2-resident: linear
//    dispatch puts column-slice x on XCD x (640 blocks = (8,80) grid).
//  - A fragments direct global->VGPR, double set, prefetched 1 jc ahead
//    (xh is 10 MB -> L3-resident; wn-pair duplication is cheap).
//  - Per m-step: 4x global_load_dwordx4 + 32 v_pk_mul_f16 + 16 MFMA.
template <int HALF_OUT>
__global__ void __launch_bounds__(256) gemm_layer(
    const _Float16* __restrict__ xh,   // (B,512) fp16
    const _Float16* __restrict__ Wh,   // (8,512,512) fp16
    const float*  __restrict__ pW,     // (B,8)
    const float*  __restrict__ pb,     // (B,8)
    const float*  __restrict__ bsv,    // (8,512)
    const float*  __restrict__ gW,     // (B,512)
    const float*  __restrict__ gb,     // (B,512)
    float* __restrict__ outf,          // (B,512) fp32 (final layer)
    _Float16* __restrict__ outh)       // (B,512) fp16 (hidden layers)
{
    const int tid  = threadIdx.x;
    const int lane = tid & 63;
    const int w    = tid >> 6;
    const int wm   = w >> 1, wn = w & 1;
    const int ln16 = lane & 15, quad = lane >> 4;
    const int bn0  = blockIdx.x * 64;
    const int bm0  = blockIdx.y * 128;

    // per-lane pW for this wave's 4 A-row groups, all 8 m, as fp16
    _Float16 pwh[4][8];
    #pragma unroll
    for (int mt = 0; mt < 4; ++mt) {
        const float* pp = pW + (size_t)(bm0 + wm * 64 + mt * 16 + ln16) * MM;
        float4 p0 = *(const float4*)pp;
        float4 p1 = *(const float4*)(pp + 4);
        pwh[mt][0] = (_Float16)p0.x; pwh[mt][1] = (_Float16)p0.y;
        pwh[mt][2] = (_Float16)p0.z; pwh[mt][3] = (_Float16)p0.w;
        pwh[mt][4] = (_Float16)p1.x; pwh[mt][5] = (_Float16)p1.y;
        pwh[mt][6] = (_Float16)p1.z; pwh[mt][7] = (_Float16)p1.w;
    }

    // per-lane fragment base pointers
    // W frag (ks,nt) of step (m,jc): row bn0+wn*32+nt*16+ln16, col jc*64+(ks*4+quad)*8
    const _Float16* wb0 = Wh + (size_t)(bn0 + wn * 32 + ln16) * DD + quad * 8;  // nt=0
    const _Float16* wb1 = wb0 + (size_t)16 * DD;                                 // nt=1
    // A frag (ks,mt) of jc: row bm0+wm*64+mt*16+ln16, col jc*64+(ks*4+quad)*8
    const _Float16* ab0 = xh + (size_t)(bm0 + wm * 64 + ln16) * DD + quad * 8;

    f4 acc[4][2] = {};

    // W register pipeline: 4 rotating sets (m&3), each {ks0nt0, ks0nt1, ks1nt0, ks1nt1}
    h8 wsa[4], wsb[4], wsc[4], wsd[4];
    h8 afr[2][4], afn[2][4];   // A fragments, current / next jc

#define WL(DST, M, JC) do {                                                   \
    const _Float16* _wp0 = wb0 + (size_t)(M) * (DD * DD) + (size_t)(JC) * 64; \
    const _Float16* _wp1 = wb1 + (size_t)(M) * (DD * DD) + (size_t)(JC) * 64; \
    DST[0] = *(const h8*)(_wp0);                                              \
    DST[1] = *(const h8*)(_wp1);                                              \
    DST[2] = *(const h8*)(_wp0 + 32);                                         \
    DST[3] = *(const h8*)(_wp1 + 32);                                         \
} while (0)

#define AL(DST, JC) do {                                                      \
    _Pragma("unroll")                                                         \
    for (int _ks = 0; _ks < 2; ++_ks)                                         \
        _Pragma("unroll")                                                     \
        for (int _mt = 0; _mt < 4; ++_mt)                                     \
            DST[_ks][_mt] = *(const h8*)(ab0 + (size_t)_mt * (16 * DD)        \
                                         + (size_t)(JC) * 64 + _ks * 32);     \
} while (0)

#define MSTEP(WS, CUR, MI) do {                                               \
    _Pragma("unroll")                                                         \
    for (int _k = 0; _k < 2; ++_k) {                                          \
        _Pragma("unroll")                                                     \
        for (int _m = 0; _m < 4; ++_m) {                                      \
            h8 _as = CUR[_k][_m] * pwh[_m][(MI)];   /* v_pk_mul_f16 x4 */     \
            acc[_m][0] = __builtin_amdgcn_mfma_f32_16x16x32_f16(              \
                _as, WS[_k * 2 + 0], acc[_m][0], 0, 0, 0);                    \
            acc[_m][1] = __builtin_amdgcn_mfma_f32_16x16x32_f16(              \
                _as, WS[_k * 2 + 1], acc[_m][1], 0, 0, 0);                    \
        }                                                                     \
    }                                                                         \
} while (0)

// One jc: 8 m-steps; W(m+2) issued 2 steps ahead into the set freed at m;
// A(jc+1) issued mid-loop; W(0/1, jc+1) issued at m=6/7 (sets a,b — matches
// next jc's use order since 8 % 4 == 0).
#define JCB(JC, CUR, NXT, PF) do {                                            \
    WL(wsc, 2, (JC));                    MSTEP(wsa, CUR, 0);                  \
    WL(wsd, 3, (JC));                    MSTEP(wsb, CUR, 1);                  \
    WL(wsa, 4, (JC));                    MSTEP(wsc, CUR, 2);                  \
    WL(wsb, 5, (JC)); if (PF) AL(NXT, (JC) + 1);                              \
                                         MSTEP(wsd, CUR, 3);                  \
    WL(wsc, 6, (JC));                    MSTEP(wsa, CUR, 4);                  \
    WL(wsd, 7, (JC));                    MSTEP(wsb, CUR, 5);                  \
    if (PF) WL(wsa, 0, (JC) + 1);        MSTEP(wsc, CUR, 6);                  \
    if (PF) WL(wsb, 1, (JC) + 1);        MSTEP(wsd, CUR, 7);                  \
} while (0)

    // prologue: first two W sets + A(0)
    WL(wsa, 0, 0);
    WL(wsb, 1, 0);
    AL(afr, 0);

    for (int jc = 0; jc < 6; jc += 2) {
        JCB(jc,     afr, afn, 1);
        JCB(jc + 1, afn, afr, 1);
    }
    JCB(6, afr, afn, 1);
    JCB(7, afn, afr, 0);

#undef JCB
#undef MSTEP
#undef AL
#undef WL

    // ---- epilogue: out = gW*acc + gb*(sum_m pb*bs) ----
    const int i0 = bn0 + wn * 32 + ln16;
    const int i1 = i0 + 16;
    float bs0[8], bs1[8];
    #pragma unroll
    for (int m2 = 0; m2 < 8; ++m2) {
        bs0[m2] = bsv[m2 * DD + i0];
        bs1[m2] = bsv[m2 * DD + i1];
    }
    #pragma unroll
    for (int mt = 0; mt < 4; ++mt) {
        #pragma unroll
        for (int r = 0; r < 4; ++r) {
            int b = bm0 + wm * 64 + mt * 16 + quad * 4 + r;
            float4 p0 = *(const float4*)(pb + (size_t)b * MM);
            float4 p1 = *(const float4*)(pb + (size_t)b * MM + 4);
            float bias0 = p0.x*bs0[0] + p0.y*bs0[1] + p0.z*bs0[2] + p0.w*bs0[3]
                        + p1.x*bs0[4] + p1.y*bs0[5] + p1.z*bs0[6] + p1.w*bs0[7];
            float bias1 = p0.x*bs1[0] + p0.y*bs1[1] + p0.z*bs1[2] + p0.w*bs1[3]
                        + p1.x*bs1[4] + p1.y*bs1[5] + p1.z*bs1[6] + p1.w*bs1[7];
            float v0 = gW[(size_t)b * DD + i0] * acc[mt][0][r] + gb[(size_t)b * DD + i0] * bias0;
            float v1 = gW[(size_t)b * DD + i1] * acc[mt][1][r] + gb[(size_t)b * DD + i1] * bias1;
            if (HALF_OUT) {
                outh[(size_t)b * DD + i0] = (_Float16)v0;
                outh[(size_t)b * DD + i1] = (_Float16)v1;
            } else {
                outf[(size_t)b * DD + i0] = v0;
                outf[(size_t)b * DD + i1] = v1;
            }
        }
    }
}

// ---------------- LayerNorm (no affine) + ELU, fp16 in/out ----------------
__global__ void __launch_bounds__(256) ln_elu_h(const _Float16* __restrict__ h,
                                                _Float16* __restrict__ xo) {
    const int w    = threadIdx.x >> 6;
    const int lane = threadIdx.x & 63;
    const int row  = blockIdx.x * 4 + w;
    h8 v = *(const h8*)(h + (size_t)row * DD + lane * 8);
    float f[8], s = 0.f, q = 0.f;
    #pragma unroll
    for (int i = 0; i < 8; ++i) { f[i] = (float)v[i]; s += f[i]; q += f[i] * f[i]; }
    #pragma unroll
    for (int off = 1; off < 64; off <<= 1) {
        s += __shfl_xor(s, off);
        q += __shfl_xor(q, off);
    }
    float mu   = s * (1.0f / 512.0f);
    float var  = q * (1.0f / 512.0f) - mu * mu;
    float rstd = rsqrtf(var + 1e-5f);
    h8 o;
    #pragma unroll
    for (int i = 0; i < 8; ++i) {
        float t = (f[i] - mu) * rstd;
        t = t > 0.0f ? t : expm1f(t);
        o[i] = (_Float16)t;
    }
    *(h8*)(xo + (size_t)row * DD + lane * 8) = o;
}

extern "C" void kernel_launch(void* const* d_in, const int* in_sizes, int n_in,
                              void* d_out, int out_size, void* d_ws, size_t ws_size,
                              hipStream_t stream) {
    const float* x   = (const float*)d_in[0];   // (B,512)
    const float* Ws  = (const float*)d_in[1];   // (3,8,512,512)
    const float* bs  = (const float*)d_in[2];   // (3,8,512)
    const float* pWs = (const float*)d_in[3];   // (3,B,8)
    const float* pbs = (const float*)d_in[4];   // (3,B,8)
    const float* gWs = (const float*)d_in[5];   // (3,B,512,1)
    const float* gbs = (const float*)d_in[6];   // (3,B,512)
    float* out = (float*)d_out;

    // workspace: Wh 12.58 MB + xh 10.49 MB + hh 10.49 MB = 32 MiB exactly
    _Float16* Wh = (_Float16*)d_ws;
    _Float16* xh = Wh + (size_t)3 * MM * DD * DD;
    _Float16* hh = xh + (size_t)BB * DD;

    const int wsl = MM * DD * DD;        // per-layer W elems
    const int bsl = MM * DD;
    const int pl  = BB * MM;
    const int gl  = BB * DD;

    cvt_f32_f16<<<3072, 256, 0, stream>>>(Ws, Wh, 786432);   // 3*8*512*512/8
    cvt_f32_f16<<<2560, 256, 0, stream>>>(x, xh, 655360);    // B*512/8

    dim3 gg(DD / 64, BB / 128);          // (8, 80): column-slice x -> XCD x

    // layer 0
    gemm_layer<1><<<gg, 256, 0, stream>>>(xh, Wh, pWs, pbs, bs, gWs, gbs,
                                          nullptr, hh);
    ln_elu_h<<<BB / 4, 256, 0, stream>>>(hh, xh);
    // layer 1
    gemm_layer<1><<<gg, 256, 0, stream>>>(xh, Wh + wsl, pWs + pl, pbs + pl,
                                          bs + bsl, gWs + gl, gbs + gl,
                                          nullptr, hh);
    ln_elu_h<<<BB / 4, 256, 0, stream>>>(hh, xh);
    // layer 2 (no LN, fp32 out)
    gemm_layer<0><<<gg, 256, 0, stream>>>(xh, Wh + 2 * wsl, pWs + 2 * pl,
                                          pbs + 2 * pl, bs + 2 * bsl,
                                          gWs + 2 * gl, gbs + 2 * gl,
                                          out, nullptr);
}

// Round 9
// 377.142 us; speedup vs baseline: 1.6380x; 1.6380x over previous
//
#include <hip/hip_runtime.h>
#include <math.h>

// Problem constants (B=10240, D=512, M=8, L=3)
#define BB   10240
#define DD   512
#define MM   8

typedef _Float16 h8 __attribute__((ext_vector_type(8)));
typedef float    f4 __attribute__((ext_vector_type(4)));

// async global->LDS DMA, 16 B per lane; LDS dst = wave-uniform base + lane*16
__device__ __forceinline__ void gload16(const void* g, void* l) {
    __builtin_amdgcn_global_load_lds(
        (__attribute__((address_space(1))) void*)(g),
        (__attribute__((address_space(3))) void*)(l), 16, 0, 0);
}

// ---------------- fp32 -> fp16 convert (8 elems/thread) ----------------
__global__ void __launch_bounds__(256) cvt_f32_f16(const float* __restrict__ s,
                                                   _Float16* __restrict__ d, int n8) {
    int i = blockIdx.x * 256 + threadIdx.x;
    if (i >= n8) return;
    const float4* sp = (const float4*)s + (size_t)i * 2;
    float4 a = sp[0], b = sp[1];
    h8 o = { (_Float16)a.x, (_Float16)a.y, (_Float16)a.z, (_Float16)a.w,
             (_Float16)b.x, (_Float16)b.y, (_Float16)b.z, (_Float16)b.w };
    *(h8*)(d + (size_t)i * 8) = o;
}

// ---------------- fused layer GEMM ----------------
// C[b,i] = gW[b,i] * sum_m pW[b,m] sum_j W[m,i,j] x[b,j]  +  gb[b,i]*sum_m pb[b,m]*bs[m,i]
//
// BARRIER-FREE + COALESCED (R8 post-mortem): reg-pipeline was scattered-load
// bound (64 distinct lines per load); LDS versions were barrier-bound.  This
// kernel stages W coalesced via global_load_lds into WAVE-PRIVATE LDS ring
// slots — completion tracked by the issuing wave's own vmcnt, so NO s_barrier
// anywhere.  3-slot ring per wave (12 KB), staged 2 m-steps ahead; counted
// s_waitcnt vmcnt(N) from exact FIFO accounting (steady 8; 16 when the 8
// A-loads at mi==3 are in the window; tail 4,0).  XOR swizzle on the global
// side (proven R0 pattern), swizzled ds_read_b128 -> <=2-way bank alias.
template <int HALF_OUT>
__global__ void __launch_bounds__(256, 3) gemm_layer(
    const _Float16* __restrict__ xh,   // (B,512) fp16
    const _Float16* __restrict__ Wh,   // (8,512,512) fp16
    const float*  __restrict__ pW,     // (B,8)
    const float*  __restrict__ pb,     // (B,8)
    const float*  __restrict__ bsv,    // (8,512)
    const float*  __restrict__ gW,     // (B,512)
    const float*  __restrict__ gb,     // (B,512)
    float* __restrict__ outf,          // (B,512) fp32 (final layer)
    _Float16* __restrict__ outh)       // (B,512) fp16 (hidden layers)
{
    // wave-private W staging: 4 waves x 3 ring slots x (32 rows x 64 cols) fp16
    __shared__ __align__(16) _Float16 Wl[4][3][32 * 64];   // 48 KB total

    const int tid  = threadIdx.x;
    const int lane = tid & 63;
    const int w    = tid >> 6;
    const int wm   = w >> 1, wn = w & 1;
    const int ln16 = lane & 15, quad = lane >> 4;
    const int bn0  = blockIdx.x * 64;
    const int bm0  = blockIdx.y * 128;

    // per-lane pW for this wave's 4 A-row groups, all 8 m, as fp16
    _Float16 pwh[4][8];
    #pragma unroll
    for (int mt = 0; mt < 4; ++mt) {
        const float* pp = pW + (size_t)(bm0 + wm * 64 + mt * 16 + ln16) * MM;
        float4 p0 = *(const float4*)pp;
        float4 p1 = *(const float4*)(pp + 4);
        pwh[mt][0] = (_Float16)p0.x; pwh[mt][1] = (_Float16)p0.y;
        pwh[mt][2] = (_Float16)p0.z; pwh[mt][3] = (_Float16)p0.w;
        pwh[mt][4] = (_Float16)p1.x; pwh[mt][5] = (_Float16)p1.y;
        pwh[mt][6] = (_Float16)p1.z; pwh[mt][7] = (_Float16)p1.w;
    }

    // A frag (ks,mt) of jc: row bm0+wm*64+mt*16+ln16, col jc*64+(ks*4+quad)*8
    const _Float16* ab0 = xh + (size_t)(bm0 + wm * 64 + ln16) * DD + quad * 8;

    f4 acc[4][2] = {};
    h8 afr[2][4], afn[2][4];   // A fragments, current / next jc

// stage this wave's 32x64 W half-tile (basis M_, k-chunk JC_) into ring slot S_
// coalesced 4x1KB; XOR swizzle applied on the GLOBAL side: LDS-phys chunk p of
// row r holds logical chunk p^(r&7).  Wave-private -> no barrier needed.
#define STW(S_, M_, JC_) do {                                                  \
    _Pragma("unroll")                                                          \
    for (int c = 0; c < 4; ++c) {                                              \
        int rit     = c * 8 + (lane >> 3);          /* row in 32-row tile */   \
        int logical = (lane & 7) ^ (lane >> 3);     /* chunk ^ (row&7) */      \
        const _Float16* gp = Wh + (size_t)(M_) * (DD * DD)                     \
                               + (size_t)(bn0 + wn * 32 + rit) * DD            \
                               + (JC_) * 64 + logical * 8;                     \
        gload16(gp, &Wl[w][S_][c * 512]);                                      \
    }                                                                          \
} while (0)

#define AL(DST, JC) do {                                                       \
    _Pragma("unroll")                                                          \
    for (int _ks = 0; _ks < 2; ++_ks)                                          \
        _Pragma("unroll")                                                      \
        for (int _mt = 0; _mt < 4; ++_mt)                                      \
            DST[_ks][_mt] = *(const h8*)(ab0 + (size_t)_mt * (16 * DD)         \
                                         + (size_t)(JC) * 64 + _ks * 32);      \
} while (0)

// one global step T_ (= jc*8 + mi): issue stage for T_+2, optional A prefetch,
// counted vmcnt wait for stage T_, swizzled ds_read, 16 MFMA.  No barriers.
#define GS(T_, N_, CUR, NXT, DOA) do {                                         \
    if ((T_) + 2 <= 63) STW((((T_) + 2) % 3), (((T_) + 2) & 7),                \
                            (((T_) + 2) >> 3));                                \
    if (DOA) AL(NXT, ((T_) >> 3) + 1);                                         \
    asm volatile("s_waitcnt vmcnt(%0)" :: "i"(N_) : "memory");                 \
    __builtin_amdgcn_sched_barrier(0);                                         \
    h8 wfr[2][2];                                                              \
    _Pragma("unroll")                                                          \
    for (int ks = 0; ks < 2; ++ks)                                             \
        _Pragma("unroll")                                                      \
        for (int nt = 0; nt < 2; ++nt) {                                       \
            int row  = nt * 16 + ln16;                                         \
            int phys = (ks * 4 + quad) ^ (ln16 & 7);                           \
            wfr[ks][nt] = *(const h8*)&Wl[w][(T_) % 3][row * 64 + phys * 8];   \
        }                                                                      \
    _Pragma("unroll")                                                          \
    for (int ks = 0; ks < 2; ++ks)                                             \
        _Pragma("unroll")                                                      \
        for (int mt = 0; mt < 4; ++mt) {                                       \
            h8 as = CUR[ks][mt] * pwh[mt][(T_) & 7];  /* v_pk_mul_f16 x4 */    \
            acc[mt][0] = __builtin_amdgcn_mfma_f32_16x16x32_f16(               \
                as, wfr[ks][0], acc[mt][0], 0, 0, 0);                          \
            acc[mt][1] = __builtin_amdgcn_mfma_f32_16x16x32_f16(               \
                as, wfr[ks][1], acc[mt][1], 0, 0, 0);                          \
        }                                                                      \
} while (0)

    // prologue: A(0) first (before S(0) -> excluded from N counts), then S(0),S(1)
    AL(afr, 0);
    STW(0, 0, 0);   // S(0) -> slot 0
    STW(1, 1, 0);   // S(1) -> slot 1

    // jc0 (CUR=afr)                    jc1 (CUR=afn)
    GS( 0,  8, afr, afn, 0);            
    GS( 1,  8, afr, afn, 0);
    GS( 2,  8, afr, afn, 0);
    GS( 3, 16, afr, afn, 1);
    GS( 4, 16, afr, afn, 0);
    GS( 5, 16, afr, afn, 0);
    GS( 6,  8, afr, afn, 0);
    GS( 7,  8, afr, afn, 0);
    GS( 8,  8, afn, afr, 0);
    GS( 9,  8, afn, afr, 0);
    GS(10,  8, afn, afr, 0);
    GS(11, 16, afn, afr, 1);
    GS(12, 16, afn, afr, 0);
    GS(13, 16, afn, afr, 0);
    GS(14,  8, afn, afr, 0);
    GS(15,  8, afn, afr, 0);
    GS(16,  8, afr, afn, 0);
    GS(17,  8, afr, afn, 0);
    GS(18,  8, afr, afn, 0);
    GS(19, 16, afr, afn, 1);
    GS(20, 16, afr, afn, 0);
    GS(21, 16, afr, afn, 0);
    GS(22,  8, afr, afn, 0);
    GS(23,  8, afr, afn, 0);
    GS(24,  8, afn, afr, 0);
    GS(25,  8, afn, afr, 0);
    GS(26,  8, afn, afr, 0);
    GS(27, 16, afn, afr, 1);
    GS(28, 16, afn, afr, 0);
    GS(29, 16, afn, afr, 0);
    GS(30,  8, afn, afr, 0);
    GS(31,  8, afn, afr, 0);
    GS(32,  8, afr, afn, 0);
    GS(33,  8, afr, afn, 0);
    GS(34,  8, afr, afn, 0);
    GS(35, 16, afr, afn, 1);
    GS(36, 16, afr, afn, 0);
    GS(37, 16, afr, afn, 0);
    GS(38,  8, afr, afn, 0);
    GS(39,  8, afr, afn, 0);
    GS(40,  8, afn, afr, 0);
    GS(41,  8, afn, afr, 0);
    GS(42,  8, afn, afr, 0);
    GS(43, 16, afn, afr, 1);
    GS(44, 16, afn, afr, 0);
    GS(45, 16, afn, afr, 0);
    GS(46,  8, afn, afr, 0);
    GS(47,  8, afn, afr, 0);
    GS(48,  8, afr, afn, 0);
    GS(49,  8, afr, afn, 0);
    GS(50,  8, afr, afn, 0);
    GS(51, 16, afr, afn, 1);
    GS(52, 16, afr, afn, 0);
    GS(53, 16, afr, afn, 0);
    GS(54,  8, afr, afn, 0);
    GS(55,  8, afr, afn, 0);
    GS(56,  8, afn, afr, 0);
    GS(57,  8, afn, afr, 0);
    GS(58,  8, afn, afr, 0);
    GS(59,  8, afn, afr, 0);
    GS(60,  8, afn, afr, 0);
    GS(61,  8, afn, afr, 0);
    GS(62,  4, afn, afr, 0);
    GS(63,  0, afn, afr, 0);

#undef GS
#undef AL
#undef STW

    // ---- epilogue: out = gW*acc + gb*(sum_m pb*bs) ----
    const int i0 = bn0 + wn * 32 + ln16;
    const int i1 = i0 + 16;
    float bs0[8], bs1[8];
    #pragma unroll
    for (int m2 = 0; m2 < 8; ++m2) {
        bs0[m2] = bsv[m2 * DD + i0];
        bs1[m2] = bsv[m2 * DD + i1];
    }
    #pragma unroll
    for (int mt = 0; mt < 4; ++mt) {
        #pragma unroll
        for (int r = 0; r < 4; ++r) {
            int b = bm0 + wm * 64 + mt * 16 + quad * 4 + r;
            float4 p0 = *(const float4*)(pb + (size_t)b * MM);
            float4 p1 = *(const float4*)(pb + (size_t)b * MM + 4);
            float bias0 = p0.x*bs0[0] + p0.y*bs0[1] + p0.z*bs0[2] + p0.w*bs0[3]
                        + p1.x*bs0[4] + p1.y*bs0[5] + p1.z*bs0[6] + p1.w*bs0[7];
            float bias1 = p0.x*bs1[0] + p0.y*bs1[1] + p0.z*bs1[2] + p0.w*bs1[3]
                        + p1.x*bs1[4] + p1.y*bs1[5] + p1.z*bs1[6] + p1.w*bs1[7];
            float v0 = gW[(size_t)b * DD + i0] * acc[mt][0][r] + gb[(size_t)b * DD + i0] * bias0;
            float v1 = gW[(size_t)b * DD + i1] * acc[mt][1][r] + gb[(size_t)b * DD + i1] * bias1;
            if (HALF_OUT) {
                outh[(size_t)b * DD + i0] = (_Float16)v0;
                outh[(size_t)b * DD + i1] = (_Float16)v1;
            } else {
                outf[(size_t)b * DD + i0] = v0;
                outf[(size_t)b * DD + i1] = v1;
            }
        }
    }
}

// ---------------- LayerNorm (no affine) + ELU, fp16 in/out ----------------
__global__ void __launch_bounds__(256) ln_elu_h(const _Float16* __restrict__ h,
                                                _Float16* __restrict__ xo) {
    const int w    = threadIdx.x >> 6;
    const int lane = threadIdx.x & 63;
    const int row  = blockIdx.x * 4 + w;
    h8 v = *(const h8*)(h + (size_t)row * DD + lane * 8);
    float f[8], s = 0.f, q = 0.f;
    #pragma unroll
    for (int i = 0; i < 8; ++i) { f[i] = (float)v[i]; s += f[i]; q += f[i] * f[i]; }
    #pragma unroll
    for (int off = 1; off < 64; off <<= 1) {
        s += __shfl_xor(s, off);
        q += __shfl_xor(q, off);
    }
    float mu   = s * (1.0f / 512.0f);
    float var  = q * (1.0f / 512.0f) - mu * mu;
    float rstd = rsqrtf(var + 1e-5f);
    h8 o;
    #pragma unroll
    for (int i = 0; i < 8; ++i) {
        float t = (f[i] - mu) * rstd;
        t = t > 0.0f ? t : expm1f(t);
        o[i] = (_Float16)t;
    }
    *(h8*)(xo + (size_t)row * DD + lane * 8) = o;
}

extern "C" void kernel_launch(void* const* d_in, const int* in_sizes, int n_in,
                              void* d_out, int out_size, void* d_ws, size_t ws_size,
                              hipStream_t stream) {
    const float* x   = (const float*)d_in[0];   // (B,512)
    const float* Ws  = (const float*)d_in[1];   // (3,8,512,512)
    const float* bs  = (const float*)d_in[2];   // (3,8,512)
    const float* pWs = (const float*)d_in[3];   // (3,B,8)
    const float* pbs = (const float*)d_in[4];   // (3,B,8)
    const float* gWs = (const float*)d_in[5];   // (3,B,512,1)
    const float* gbs = (const float*)d_in[6];   // (3,B,512)
    float* out = (float*)d_out;

    // workspace: Wh 12.58 MB + xh 10.49 MB + hh 10.49 MB = 32 MiB exactly
    _Float16* Wh = (_Float16*)d_ws;
    _Float16* xh = Wh + (size_t)3 * MM * DD * DD;
    _Float16* hh = xh + (size_t)BB * DD;

    const int wsl = MM * DD * DD;        // per-layer W elems
    const int bsl = MM * DD;
    const int pl  = BB * MM;
    const int gl  = BB * DD;

    cvt_f32_f16<<<3072, 256, 0, stream>>>(Ws, Wh, 786432);   // 3*8*512*512/8
    cvt_f32_f16<<<2560, 256, 0, stream>>>(x, xh, 655360);    // B*512/8

    dim3 gg(DD / 64, BB / 128);          // (8, 80): column-slice x -> XCD x

    // layer 0
    gemm_layer<1><<<gg, 256, 0, stream>>>(xh, Wh, pWs, pbs, bs, gWs, gbs,
                                          nullptr, hh);
    ln_elu_h<<<BB / 4, 256, 0, stream>>>(hh, xh);
    // layer 1
    gemm_layer<1><<<gg, 256, 0, stream>>>(xh, Wh + wsl, pWs + pl, pbs + pl,
                                          bs + bsl, gWs + gl, gbs + gl,
                                          nullptr, hh);
    ln_elu_h<<<BB / 4, 256, 0, stream>>>(hh, xh);
    // layer 2 (no LN, fp32 out)
    gemm_layer<0><<<gg, 256, 0, stream>>>(xh, Wh + 2 * wsl, pWs + 2 * pl,
                                          pbs + 2 * pl, bs + 2 * bsl,
                                          gWs + 2 * gl, gbs + 2 * gl,
                                          out, nullptr);
}

// Round 10
// 374.521 us; speedup vs baseline: 1.6495x; 1.0070x over previous
//
#include <hip/hip_runtime.h>
#include <math.h>

// Problem constants (B=10240, D=512, M=8, L=3)
#define BB   10240
#define DD   512
#define MM   8

typedef _Float16 h8 __attribute__((ext_vector_type(8)));
typedef float    f4 __attribute__((ext_vector_type(4)));

// async global->LDS DMA, 16 B per lane; LDS dst = wave-uniform base + lane*16
__device__ __forceinline__ void gload16(const void* g, void* l) {
    __builtin_amdgcn_global_load_lds(
        (__attribute__((address_space(1))) void*)(g),
        (__attribute__((address_space(3))) void*)(l), 16, 0, 0);
}

// ---------------- fp32 -> fp16 convert (8 elems/thread) ----------------
__global__ void __launch_bounds__(256) cvt_f32_f16(const float* __restrict__ s,
                                                   _Float16* __restrict__ d, int n8) {
    int i = blockIdx.x * 256 + threadIdx.x;
    if (i >= n8) return;
    const float4* sp = (const float4*)s + (size_t)i * 2;
    float4 a = sp[0], b = sp[1];
    h8 o = { (_Float16)a.x, (_Float16)a.y, (_Float16)a.z, (_Float16)a.w,
             (_Float16)b.x, (_Float16)b.y, (_Float16)b.z, (_Float16)b.w };
    *(h8*)(d + (size_t)i * 8) = o;
}

// ---------------- fused layer GEMM ----------------
// C[b,i] = gW[b,i] * sum_m pW[b,m] sum_j W[m,i,j] x[b,j]  +  gb[b,i]*sum_m pb[b,m]*bs[m,i]
//
// R9 -> R10: ZERO-DUPLICATION staging.  R9's (wm,wn) mapping staged each W
// half-tile twice per block (waves sharing wn).  Now: 128-thread blocks,
// 2 waves, each wave owns an exclusive 32-col W half (staged exactly once)
// and computes 128 A-rows x 32 W-cols -> 32 MFMA per vmcnt-wait (2x R9).
// Still wave-private LDS ring (3 slots x 4 KB/wave), ZERO barriers, counted
// vmcnt from exact FIFO: steady 8; 24 at mi==0 (16 A-loads in window);
// tail 4,0.  A frags single-buffered; next-jc A issued at mi==7 right after
// last use (partial cover, no extra VGPR).  XOR swizzle unchanged (0 bank
// conflicts measured).
template <int HALF_OUT>
__global__ void __launch_bounds__(128, 2) gemm_layer(
    const _Float16* __restrict__ xh,   // (B,512) fp16
    const _Float16* __restrict__ Wh,   // (8,512,512) fp16
    const float*  __restrict__ pW,     // (B,8)
    const float*  __restrict__ pb,     // (B,8)
    const float*  __restrict__ bsv,    // (8,512)
    const float*  __restrict__ gW,     // (B,512)
    const float*  __restrict__ gb,     // (B,512)
    float* __restrict__ outf,          // (B,512) fp32 (final layer)
    _Float16* __restrict__ outh)       // (B,512) fp16 (hidden layers)
{
    // wave-private W staging: 2 waves x 3 ring slots x (32 rows x 64 cols) fp16
    __shared__ __align__(16) _Float16 Wl[2][3][32 * 64];   // 24 KB total

    const int tid  = threadIdx.x;
    const int lane = tid & 63;
    const int w    = tid >> 6;           // wave 0/1 -> W cols [w*32, w*32+32)
    const int ln16 = lane & 15, quad = lane >> 4;
    const int bn0  = blockIdx.x * 64;
    const int bm0  = blockIdx.y * 128;

    // per-lane pW for all 8 A-row groups (128 rows), all 8 m, as fp16
    _Float16 pwh[8][8];
    #pragma unroll
    for (int mt = 0; mt < 8; ++mt) {
        const float* pp = pW + (size_t)(bm0 + mt * 16 + ln16) * MM;
        float4 p0 = *(const float4*)pp;
        float4 p1 = *(const float4*)(pp + 4);
        pwh[mt][0] = (_Float16)p0.x; pwh[mt][1] = (_Float16)p0.y;
        pwh[mt][2] = (_Float16)p0.z; pwh[mt][3] = (_Float16)p0.w;
        pwh[mt][4] = (_Float16)p1.x; pwh[mt][5] = (_Float16)p1.y;
        pwh[mt][6] = (_Float16)p1.z; pwh[mt][7] = (_Float16)p1.w;
    }

    // A frag (ks,mt) of jc: row bm0+mt*16+ln16, col jc*64+(ks*4+quad)*8
    const _Float16* ab0 = xh + (size_t)(bm0 + ln16) * DD + quad * 8;

    f4 acc[8][2] = {};
    h8 afr[2][8];   // A fragments, single-buffered (16 h8 = 64 VGPR)

// stage this wave's 32x64 W half-tile (basis M_, k-chunk JC_) into ring slot S_
// coalesced 4x1KB; XOR swizzle on the GLOBAL side: LDS-phys chunk p of row r
// holds logical chunk p^(r&7).  Wave-private -> no barrier needed.
#define STW(S_, M_, JC_) do {                                                  \
    _Pragma("unroll")                                                          \
    for (int c = 0; c < 4; ++c) {                                              \
        int rit     = c * 8 + (lane >> 3);          /* row in 32-row tile */   \
        int logical = (lane & 7) ^ (lane >> 3);     /* chunk ^ (row&7) */      \
        const _Float16* gp = Wh + (size_t)(M_) * (DD * DD)                     \
                               + (size_t)(bn0 + w * 32 + rit) * DD             \
                               + (JC_) * 64 + logical * 8;                     \
        gload16(gp, &Wl[w][S_][c * 512]);                                      \
    }                                                                          \
} while (0)

#define AL(JC) do {                                                            \
    _Pragma("unroll")                                                          \
    for (int _ks = 0; _ks < 2; ++_ks)                                          \
        _Pragma("unroll")                                                      \
        for (int _mt = 0; _mt < 8; ++_mt)                                      \
            afr[_ks][_mt] = *(const h8*)(ab0 + (size_t)_mt * (16 * DD)         \
                                         + (size_t)(JC) * 64 + _ks * 32);      \
} while (0)

// one global step T_ (= jc*8 + mi): issue stage for T_+2, counted vmcnt wait
// for stage T_, swizzled ds_read, 32 MFMA; optionally issue next-jc A loads
// AFTER the last afr use (PA_).  No barriers anywhere.
#define GS(T_, N_, PA_) do {                                                   \
    if ((T_) + 2 <= 63) STW((((T_) + 2) % 3), (((T_) + 2) & 7),                \
                            (((T_) + 2) >> 3));                                \
    asm volatile("s_waitcnt vmcnt(%0)" :: "i"(N_) : "memory");                 \
    __builtin_amdgcn_sched_barrier(0);                                         \
    h8 wfr[2][2];                                                              \
    _Pragma("unroll")                                                          \
    for (int ks = 0; ks < 2; ++ks)                                             \
        _Pragma("unroll")                                                      \
        for (int nt = 0; nt < 2; ++nt) {                                       \
            int row  = nt * 16 + ln16;                                         \
            int phys = (ks * 4 + quad) ^ (ln16 & 7);                           \
            wfr[ks][nt] = *(const h8*)&Wl[w][(T_) % 3][row * 64 + phys * 8];   \
        }                                                                      \
    _Pragma("unroll")                                                          \
    for (int ks = 0; ks < 2; ++ks)                                             \
        _Pragma("unroll")                                                      \
        for (int mt = 0; mt < 8; ++mt) {                                       \
            h8 as = afr[ks][mt] * pwh[mt][(T_) & 7];  /* v_pk_mul_f16 x4 */    \
            acc[mt][0] = __builtin_amdgcn_mfma_f32_16x16x32_f16(               \
                as, wfr[ks][0], acc[mt][0], 0, 0, 0);                          \
            acc[mt][1] = __builtin_amdgcn_mfma_f32_16x16x32_f16(               \
                as, wfr[ks][1], acc[mt][1], 0, 0, 0);                          \
        }                                                                      \
    if (PA_) AL(((T_) >> 3) + 1);                                              \
} while (0)

    // prologue: A(0) first (ahead of W in FIFO), then slots 0,1
    AL(0);
    STW(0, 0, 0);
    STW(1, 1, 0);

    // jc=0: T=0 needs vmcnt(8) (retires prologue A + W_0, leaves W_1,W_2)
    GS( 0,  8, 0); GS( 1,  8, 0); GS( 2,  8, 0); GS( 3,  8, 0);
    GS( 4,  8, 0); GS( 5,  8, 0); GS( 6,  8, 0); GS( 7,  8, 1);
    // jc=1..6: mi==0 has 16 A-loads in window -> 24; PA at mi==7
    GS( 8, 24, 0); GS( 9,  8, 0); GS(10,  8, 0); GS(11,  8, 0);
    GS(12,  8, 0); GS(13,  8, 0); GS(14,  8, 0); GS(15,  8, 1);
    GS(16, 24, 0); GS(17,  8, 0); GS(18,  8, 0); GS(19,  8, 0);
    GS(20,  8, 0); GS(21,  8, 0); GS(22,  8, 0); GS(23,  8, 1);
    GS(24, 24, 0); GS(25,  8, 0); GS(26,  8, 0); GS(27,  8, 0);
    GS(28,  8, 0); GS(29,  8, 0); GS(30,  8, 0); GS(31,  8, 1);
    GS(32, 24, 0); GS(33,  8, 0); GS(34,  8, 0); GS(35,  8, 0);
    GS(36,  8, 0); GS(37,  8, 0); GS(38,  8, 0); GS(39,  8, 1);
    GS(40, 24, 0); GS(41,  8, 0); GS(42,  8, 0); GS(43,  8, 0);
    GS(44,  8, 0); GS(45,  8, 0); GS(46,  8, 0); GS(47,  8, 1);
    GS(48, 24, 0); GS(49,  8, 0); GS(50,  8, 0); GS(51,  8, 0);
    GS(52,  8, 0); GS(53,  8, 0); GS(54,  8, 0); GS(55,  8, 1);
    // jc=7: no further A; ring drains 8,...,8,4,0
    GS(56, 24, 0); GS(57,  8, 0); GS(58,  8, 0); GS(59,  8, 0);
    GS(60,  8, 0); GS(61,  8, 0); GS(62,  4, 0); GS(63,  0, 0);

#undef GS
#undef AL
#undef STW

    // ---- epilogue: out = gW*acc + gb*(sum_m pb*bs) ----
    const int i0 = bn0 + w * 32 + ln16;
    const int i1 = i0 + 16;
    float bs0[8], bs1[8];
    #pragma unroll
    for (int m2 = 0; m2 < 8; ++m2) {
        bs0[m2] = bsv[m2 * DD + i0];
        bs1[m2] = bsv[m2 * DD + i1];
    }
    #pragma unroll
    for (int mt = 0; mt < 8; ++mt) {
        #pragma unroll
        for (int r = 0; r < 4; ++r) {
            int b = bm0 + mt * 16 + quad * 4 + r;
            float4 p0 = *(const float4*)(pb + (size_t)b * MM);
            float4 p1 = *(const float4*)(pb + (size_t)b * MM + 4);
            float bias0 = p0.x*bs0[0] + p0.y*bs0[1] + p0.z*bs0[2] + p0.w*bs0[3]
                        + p1.x*bs0[4] + p1.y*bs0[5] + p1.z*bs0[6] + p1.w*bs0[7];
            float bias1 = p0.x*bs1[0] + p0.y*bs1[1] + p0.z*bs1[2] + p0.w*bs1[3]
                        + p1.x*bs1[4] + p1.y*bs1[5] + p1.z*bs1[6] + p1.w*bs1[7];
            float v0 = gW[(size_t)b * DD + i0] * acc[mt][0][r] + gb[(size_t)b * DD + i0] * bias0;
            float v1 = gW[(size_t)b * DD + i1] * acc[mt][1][r] + gb[(size_t)b * DD + i1] * bias1;
            if (HALF_OUT) {
                outh[(size_t)b * DD + i0] = (_Float16)v0;
                outh[(size_t)b * DD + i1] = (_Float16)v1;
            } else {
                outf[(size_t)b * DD + i0] = v0;
                outf[(size_t)b * DD + i1] = v1;
            }
        }
    }
}

// ---------------- LayerNorm (no affine) + ELU, fp16 in/out ----------------
__global__ void __launch_bounds__(256) ln_elu_h(const _Float16* __restrict__ h,
                                                _Float16* __restrict__ xo) {
    const int w    = threadIdx.x >> 6;
    const int lane = threadIdx.x & 63;
    const int row  = blockIdx.x * 4 + w;
    h8 v = *(const h8*)(h + (size_t)row * DD + lane * 8);
    float f[8], s = 0.f, q = 0.f;
    #pragma unroll
    for (int i = 0; i < 8; ++i) { f[i] = (float)v[i]; s += f[i]; q += f[i] * f[i]; }
    #pragma unroll
    for (int off = 1; off < 64; off <<= 1) {
        s += __shfl_xor(s, off);
        q += __shfl_xor(q, off);
    }
    float mu   = s * (1.0f / 512.0f);
    float var  = q * (1.0f / 512.0f) - mu * mu;
    float rstd = rsqrtf(var + 1e-5f);
    h8 o;
    #pragma unroll
    for (int i = 0; i < 8; ++i) {
        float t = (f[i] - mu) * rstd;
        t = t > 0.0f ? t : expm1f(t);
        o[i] = (_Float16)t;
    }
    *(h8*)(xo + (size_t)row * DD + lane * 8) = o;
}

extern "C" void kernel_launch(void* const* d_in, const int* in_sizes, int n_in,
                              void* d_out, int out_size, void* d_ws, size_t ws_size,
                              hipStream_t stream) {
    const float* x   = (const float*)d_in[0];   // (B,512)
    const float* Ws  = (const float*)d_in[1];   // (3,8,512,512)
    const float* bs  = (const float*)d_in[2];   // (3,8,512)
    const float* pWs = (const float*)d_in[3];   // (3,B,8)
    const float* pbs = (const float*)d_in[4];   // (3,B,8)
    const float* gWs = (const float*)d_in[5];   // (3,B,512,1)
    const float* gbs = (const float*)d_in[6];   // (3,B,512)
    float* out = (float*)d_out;

    // workspace: Wh 12.58 MB + xh 10.49 MB + hh 10.49 MB = 32 MiB exactly
    _Float16* Wh = (_Float16*)d_ws;
    _Float16* xh = Wh + (size_t)3 * MM * DD * DD;
    _Float16* hh = xh + (size_t)BB * DD;

    const int wsl = MM * DD * DD;        // per-layer W elems
    const int bsl = MM * DD;
    const int pl  = BB * MM;
    const int gl  = BB * DD;

    cvt_f32_f16<<<3072, 256, 0, stream>>>(Ws, Wh, 786432);   // 3*8*512*512/8
    cvt_f32_f16<<<2560, 256, 0, stream>>>(x, xh, 655360);    // B*512/8

    dim3 gg(DD / 64, BB / 128);          // (8, 80): column-slice x -> XCD x

    // layer 0
    gemm_layer<1><<<gg, 128, 0, stream>>>(xh, Wh, pWs, pbs, bs, gWs, gbs,
                                          nullptr, hh);
    ln_elu_h<<<BB / 4, 256, 0, stream>>>(hh, xh);
    // layer 1
    gemm_layer<1><<<gg, 128, 0, stream>>>(xh, Wh + wsl, pWs + pl, pbs + pl,
                                          bs + bsl, gWs + gl, gbs + gl,
                                          nullptr, hh);
    ln_elu_h<<<BB / 4, 256, 0, stream>>>(hh, xh);
    // layer 2 (no LN, fp32 out)
    gemm_layer<0><<<gg, 128, 0, stream>>>(xh, Wh + 2 * wsl, pWs + 2 * pl,
                                          pbs + 2 * pl, bs + 2 * bsl,
                                          gWs + 2 * gl, gbs + 2 * gl,
                                          out, nullptr);
}

// Round 12
// 361.249 us; speedup vs baseline: 1.7101x; 1.0367x over previous
//
#include <hip/hip_runtime.h>
#include <math.h>

// Problem constants (B=10240, D=512, M=8, L=3)
#define BB   10240
#define DD   512
#define MM   8

typedef _Float16 h8 __attribute__((ext_vector_type(8)));
typedef float    f4 __attribute__((ext_vector_type(4)));

// async global->LDS DMA, 16 B per lane; LDS dst = wave-uniform base + lane*16
__device__ __forceinline__ void gload16(const void* g, void* l) {
    __builtin_amdgcn_global_load_lds(
        (__attribute__((address_space(1))) void*)(g),
        (__attribute__((address_space(3))) void*)(l), 16, 0, 0);
}

// ---------------- fp32 -> fp16 convert (8 elems/thread) ----------------
__global__ void __launch_bounds__(256) cvt_f32_f16(const float* __restrict__ s,
                                                   _Float16* __restrict__ d, int n8) {
    int i = blockIdx.x * 256 + threadIdx.x;
    if (i >= n8) return;
    const float4* sp = (const float4*)s + (size_t)i * 2;
    float4 a = sp[0], b = sp[1];
    h8 o = { (_Float16)a.x, (_Float16)a.y, (_Float16)a.z, (_Float16)a.w,
             (_Float16)b.x, (_Float16)b.y, (_Float16)b.z, (_Float16)b.w };
    *(h8*)(d + (size_t)i * 8) = o;
}

// ---------------- fused layer GEMM ----------------
// C[b,i] = gW[b,i] * sum_m pW[b,m] sum_j W[m,i,j] x[b,j]  +  gb[b,i]*sum_m pb[b,m]*bs[m,i]
//
// R10 -> R11: COALESCED A (kill the FIFO poison).  R9/R10 evidence: staging
// bytes and occupancy are not the limiter; both shared scattered A-loads
// (64 lines/instr, L3 latency) in the same IN-ORDER vmcnt FIFO as W stages —
// every W stage issued after an A block inherits the scatter's latency.
// Now A is staged coalesced into block-shared LDS (16 KB tile, 8x1KB per
// wave, global-side XOR swizzle), afr read once per jc via swizzled
// ds_read_b128.  Costs 2 barriers per jc (16 total, vs R5's 128).
// W path unchanged: wave-private 3-slot ring, 2-step lead, counted vmcnt.
// Steady-jc N = [8,8,8,16,16,8,8,8]: A8 in window at mi3/4; mi5's vmcnt(8)
// forces A retired (in-order) before barrier#1 at mi7.  Tail 4,0.
template <int HALF_OUT>
__global__ void __launch_bounds__(128, 2) gemm_layer(
    const _Float16* __restrict__ xh,   // (B,512) fp16
    const _Float16* __restrict__ Wh,   // (8,512,512) fp16
    const float*  __restrict__ pW,     // (B,8)
    const float*  __restrict__ pb,     // (B,8)
    const float*  __restrict__ bsv,    // (8,512)
    const float*  __restrict__ gW,     // (B,512)
    const float*  __restrict__ gb,     // (B,512)
    float* __restrict__ outf,          // (B,512) fp32 (final layer)
    _Float16* __restrict__ outh)       // (B,512) fp16 (hidden layers)
{
    // W: wave-private ring, 2 waves x 3 slots x (32 rows x 64 cols) = 24 KB
    __shared__ __align__(16) _Float16 Wl[2][3][32 * 64];
    // A: block-shared single buffer, 128 rows x 64 cols = 16 KB
    __shared__ __align__(16) _Float16 Ab[128 * 64];

    const int tid  = threadIdx.x;
    const int lane = tid & 63;
    const int w    = tid >> 6;           // wave 0/1 -> W cols [w*32, w*32+32)
    const int ln16 = lane & 15, quad = lane >> 4;
    const int bn0  = blockIdx.x * 64;
    const int bm0  = blockIdx.y * 128;

    // per-lane pW for all 8 A-row groups (128 rows), all 8 m, as fp16
    _Float16 pwh[8][8];
    #pragma unroll
    for (int mt = 0; mt < 8; ++mt) {
        const float* pp = pW + (size_t)(bm0 + mt * 16 + ln16) * MM;
        float4 p0 = *(const float4*)pp;
        float4 p1 = *(const float4*)(pp + 4);
        pwh[mt][0] = (_Float16)p0.x; pwh[mt][1] = (_Float16)p0.y;
        pwh[mt][2] = (_Float16)p0.z; pwh[mt][3] = (_Float16)p0.w;
        pwh[mt][4] = (_Float16)p1.x; pwh[mt][5] = (_Float16)p1.y;
        pwh[mt][6] = (_Float16)p1.z; pwh[mt][7] = (_Float16)p1.w;
    }

    f4 acc[8][2] = {};
    h8 afr[2][8];   // A fragments for current jc (read from Ab once per jc)

// stage wave's 32x64 W half-tile (basis M_, k-chunk JC_) into ring slot S_
// coalesced 4x1KB; XOR swizzle on the GLOBAL side.  Wave-private.
#define STW(S_, M_, JC_) do {                                                  \
    _Pragma("unroll")                                                          \
    for (int c = 0; c < 4; ++c) {                                              \
        int rit     = c * 8 + (lane >> 3);                                     \
        int logical = (lane & 7) ^ (lane >> 3);                                \
        const _Float16* gp = Wh + (size_t)(M_) * (DD * DD)                     \
                               + (size_t)(bn0 + w * 32 + rit) * DD             \
                               + (JC_) * 64 + logical * 8;                     \
        gload16(gp, &Wl[w][S_][c * 512]);                                      \
    }                                                                          \
} while (0)

// stage A(jc) tile (128 rows x 64 cols) into Ab; wave w does rows w*64..+64
// (8x1KB coalesced, global-side XOR swizzle).  Block-shared.
#define STA(JC_) do {                                                          \
    _Pragma("unroll")                                                          \
    for (int c = 0; c < 8; ++c) {                                              \
        int rit     = w * 64 + c * 8 + (lane >> 3);                            \
        int logical = (lane & 7) ^ (lane >> 3);                                \
        const _Float16* gp = xh + (size_t)(bm0 + rit) * DD                     \
                                + (JC_) * 64 + logical * 8;                    \
        gload16(gp, &Ab[rit * 64]);                                            \
    }                                                                          \
} while (0)

// read all 16 A fragments for this jc from Ab (swizzled ds_read_b128)
#define AFR() do {                                                             \
    _Pragma("unroll")                                                          \
    for (int _ks = 0; _ks < 2; ++_ks)                                          \
        _Pragma("unroll")                                                      \
        for (int _mt = 0; _mt < 8; ++_mt) {                                    \
            int _phys = (_ks * 4 + quad) ^ (ln16 & 7);                         \
            afr[_ks][_mt] = *(const h8*)&Ab[(_mt * 16 + ln16) * 64             \
                                            + _phys * 8];                      \
        }                                                                      \
} while (0)

// one step T_ (= jc*8+mi): STW(T+2), counted vmcnt, [afr], wfr, 32 MFMA,
// [stage A(jc+1)], [barrier#2 after afr-consume], [barrier#1 at jc end].
#define GS(T_, N_, AF_, SA_, B1_, B2_) do {                                    \
    if ((T_) + 2 <= 63) STW((((T_) + 2) % 3), (((T_) + 2) & 7),                \
                            (((T_) + 2) >> 3));                                \
    asm volatile("s_waitcnt vmcnt(%0)" :: "i"(N_) : "memory");                 \
    __builtin_amdgcn_sched_barrier(0);                                         \
    if (AF_) AFR();                                                            \
    h8 wfr[2][2];                                                              \
    _Pragma("unroll")                                                          \
    for (int ks = 0; ks < 2; ++ks)                                             \
        _Pragma("unroll")                                                      \
        for (int nt = 0; nt < 2; ++nt) {                                       \
            int row  = nt * 16 + ln16;                                         \
            int phys = (ks * 4 + quad) ^ (ln16 & 7);                           \
            wfr[ks][nt] = *(const h8*)&Wl[w][(T_) % 3][row * 64 + phys * 8];   \
        }                                                                      \
    _Pragma("unroll")                                                          \
    for (int ks = 0; ks < 2; ++ks)                                             \
        _Pragma("unroll")                                                      \
        for (int mt = 0; mt < 8; ++mt) {                                       \
            h8 as = afr[ks][mt] * pwh[mt][(T_) & 7];  /* v_pk_mul_f16 x4 */    \
            acc[mt][0] = __builtin_amdgcn_mfma_f32_16x16x32_f16(               \
                as, wfr[ks][0], acc[mt][0], 0, 0, 0);                          \
            acc[mt][1] = __builtin_amdgcn_mfma_f32_16x16x32_f16(               \
                as, wfr[ks][1], acc[mt][1], 0, 0, 0);                          \
        }                                                                      \
    if (SA_) STA(((T_) >> 3) + 1);                                             \
    if (B2_) { asm volatile("s_waitcnt lgkmcnt(0)" ::: "memory");              \
               __builtin_amdgcn_s_barrier();                                   \
               asm volatile("" ::: "memory"); }                                \
    if (B1_) { __builtin_amdgcn_s_barrier();                                   \
               asm volatile("" ::: "memory"); }                                \
} while (0)

    // prologue: A(0) then W0,W1; force A retired (vmcnt(8) leaves W0,W1);
    // barrier publishes A(0) to both waves.
    STA(0);
    STW(0, 0, 0);
    STW(1, 1, 0);
    asm volatile("s_waitcnt vmcnt(8)" ::: "memory");
    __builtin_amdgcn_sched_barrier(0);
    __builtin_amdgcn_s_barrier();
    asm volatile("" ::: "memory");

    //   T   N  AF SA B1 B2
    GS(  0,  8, 1, 0, 0, 1);
    GS(  1,  8, 0, 0, 0, 0);
    GS(  2,  8, 0, 1, 0, 0);
    GS(  3, 16, 0, 0, 0, 0);
    GS(  4, 16, 0, 0, 0, 0);
    GS(  5,  8, 0, 0, 0, 0);
    GS(  6,  8, 0, 0, 0, 0);
    GS(  7,  8, 0, 0, 1, 0);
    GS(  8,  8, 1, 0, 0, 1);
    GS(  9,  8, 0, 0, 0, 0);
    GS( 10,  8, 0, 1, 0, 0);
    GS( 11, 16, 0, 0, 0, 0);
    GS( 12, 16, 0, 0, 0, 0);
    GS( 13,  8, 0, 0, 0, 0);
    GS( 14,  8, 0, 0, 0, 0);
    GS( 15,  8, 0, 0, 1, 0);
    GS( 16,  8, 1, 0, 0, 1);
    GS( 17,  8, 0, 0, 0, 0);
    GS( 18,  8, 0, 1, 0, 0);
    GS( 19, 16, 0, 0, 0, 0);
    GS( 20, 16, 0, 0, 0, 0);
    GS( 21,  8, 0, 0, 0, 0);
    GS( 22,  8, 0, 0, 0, 0);
    GS( 23,  8, 0, 0, 1, 0);
    GS( 24,  8, 1, 0, 0, 1);
    GS( 25,  8, 0, 0, 0, 0);
    GS( 26,  8, 0, 1, 0, 0);
    GS( 27, 16, 0, 0, 0, 0);
    GS( 28, 16, 0, 0, 0, 0);
    GS( 29,  8, 0, 0, 0, 0);
    GS( 30,  8, 0, 0, 0, 0);
    GS( 31,  8, 0, 0, 1, 0);
    GS( 32,  8, 1, 0, 0, 1);
    GS( 33,  8, 0, 0, 0, 0);
    GS( 34,  8, 0, 1, 0, 0);
    GS( 35, 16, 0, 0, 0, 0);
    GS( 36, 16, 0, 0, 0, 0);
    GS( 37,  8, 0, 0, 0, 0);
    GS( 38,  8, 0, 0, 0, 0);
    GS( 39,  8, 0, 0, 1, 0);
    GS( 40,  8, 1, 0, 0, 1);
    GS( 41,  8, 0, 0, 0, 0);
    GS( 42,  8, 0, 1, 0, 0);
    GS( 43, 16, 0, 0, 0, 0);
    GS( 44, 16, 0, 0, 0, 0);
    GS( 45,  8, 0, 0, 0, 0);
    GS( 46,  8, 0, 0, 0, 0);
    GS( 47,  8, 0, 0, 1, 0);
    GS( 48,  8, 1, 0, 0, 1);
    GS( 49,  8, 0, 0, 0, 0);
    GS( 50,  8, 0, 1, 0, 0);   // stages A(7)
    GS( 51, 16, 0, 0, 0, 0);
    GS( 52, 16, 0, 0, 0, 0);
    GS( 53,  8, 0, 0, 0, 0);
    GS( 54,  8, 0, 0, 0, 0);
    GS( 55,  8, 0, 0, 1, 0);
    GS( 56,  8, 1, 0, 0, 0);   // jc=7: no re-stage, no barriers
    GS( 57,  8, 0, 0, 0, 0);
    GS( 58,  8, 0, 0, 0, 0);
    GS( 59,  8, 0, 0, 0, 0);
    GS( 60,  8, 0, 0, 0, 0);
    GS( 61,  8, 0, 0, 0, 0);
    GS( 62,  4, 0, 0, 0, 0);
    GS( 63,  0, 0, 0, 0, 0);

#undef GS
#undef AFR
#undef STA
#undef STW

    // ---- epilogue: out = gW*acc + gb*(sum_m pb*bs) ----
    const int i0 = bn0 + w * 32 + ln16;
    const int i1 = i0 + 16;
    float bs0[8], bs1[8];
    #pragma unroll
    for (int m2 = 0; m2 < 8; ++m2) {
        bs0[m2] = bsv[m2 * DD + i0];
        bs1[m2] = bsv[m2 * DD + i1];
    }
    #pragma unroll
    for (int mt = 0; mt < 8; ++mt) {
        #pragma unroll
        for (int r = 0; r < 4; ++r) {
            int b = bm0 + mt * 16 + quad * 4 + r;
            float4 p0 = *(const float4*)(pb + (size_t)b * MM);
            float4 p1 = *(const float4*)(pb + (size_t)b * MM + 4);
            float bias0 = p0.x*bs0[0] + p0.y*bs0[1] + p0.z*bs0[2] + p0.w*bs0[3]
                        + p1.x*bs0[4] + p1.y*bs0[5] + p1.z*bs0[6] + p1.w*bs0[7];
            float bias1 = p0.x*bs1[0] + p0.y*bs1[1] + p0.z*bs1[2] + p0.w*bs1[3]
                        + p1.x*bs1[4] + p1.y*bs1[5] + p1.z*bs1[6] + p1.w*bs1[7];
            float v0 = gW[(size_t)b * DD + i0] * acc[mt][0][r] + gb[(size_t)b * DD + i0] * bias0;
            float v1 = gW[(size_t)b * DD + i1] * acc[mt][1][r] + gb[(size_t)b * DD + i1] * bias1;
            if (HALF_OUT) {
                outh[(size_t)b * DD + i0] = (_Float16)v0;
                outh[(size_t)b * DD + i1] = (_Float16)v1;
            } else {
                outf[(size_t)b * DD + i0] = v0;
                outf[(size_t)b * DD + i1] = v1;
            }
        }
    }
}

// ---------------- LayerNorm (no affine) + ELU, fp16 in/out ----------------
__global__ void __launch_bounds__(256) ln_elu_h(const _Float16* __restrict__ h,
                                                _Float16* __restrict__ xo) {
    const int w    = threadIdx.x >> 6;
    const int lane = threadIdx.x & 63;
    const int row  = blockIdx.x * 4 + w;
    h8 v = *(const h8*)(h + (size_t)row * DD + lane * 8);
    float f[8], s = 0.f, q = 0.f;
    #pragma unroll
    for (int i = 0; i < 8; ++i) { f[i] = (float)v[i]; s += f[i]; q += f[i] * f[i]; }
    #pragma unroll
    for (int off = 1; off < 64; off <<= 1) {
        s += __shfl_xor(s, off);
        q += __shfl_xor(q, off);
    }
    float mu   = s * (1.0f / 512.0f);
    float var  = q * (1.0f / 512.0f) - mu * mu;
    float rstd = rsqrtf(var + 1e-5f);
    h8 o;
    #pragma unroll
    for (int i = 0; i < 8; ++i) {
        float t = (f[i] - mu) * rstd;
        t = t > 0.0f ? t : expm1f(t);
        o[i] = (_Float16)t;
    }
    *(h8*)(xo + (size_t)row * DD + lane * 8) = o;
}

extern "C" void kernel_launch(void* const* d_in, const int* in_sizes, int n_in,
                              void* d_out, int out_size, void* d_ws, size_t ws_size,
                              hipStream_t stream) {
    const float* x   = (const float*)d_in[0];   // (B,512)
    const float* Ws  = (const float*)d_in[1];   // (3,8,512,512)
    const float* bs  = (const float*)d_in[2];   // (3,8,512)
    const float* pWs = (const float*)d_in[3];   // (3,B,8)
    const float* pbs = (const float*)d_in[4];   // (3,B,8)
    const float* gWs = (const float*)d_in[5];   // (3,B,512,1)
    const float* gbs = (const float*)d_in[6];   // (3,B,512)
    float* out = (float*)d_out;

    // workspace: Wh 12.58 MB + xh 10.49 MB + hh 10.49 MB = 32 MiB exactly
    _Float16* Wh = (_Float16*)d_ws;
    _Float16* xh = Wh + (size_t)3 * MM * DD * DD;
    _Float16* hh = xh + (size_t)BB * DD;

    const int wsl = MM * DD * DD;        // per-layer W elems
    const int bsl = MM * DD;
    const int pl  = BB * MM;
    const int gl  = BB * DD;

    cvt_f32_f16<<<3072, 256, 0, stream>>>(Ws, Wh, 786432);   // 3*8*512*512/8
    cvt_f32_f16<<<2560, 256, 0, stream>>>(x, xh, 655360);    // B*512/8

    dim3 gg(DD / 64, BB / 128);          // (8, 80): column-slice x -> XCD x

    // layer 0
    gemm_layer<1><<<gg, 128, 0, stream>>>(xh, Wh, pWs, pbs, bs, gWs, gbs,
                                          nullptr, hh);
    ln_elu_h<<<BB / 4, 256, 0, stream>>>(hh, xh);
    // layer 1
    gemm_layer<1><<<gg, 128, 0, stream>>>(xh, Wh + wsl, pWs + pl, pbs + pl,
                                          bs + bsl, gWs + gl, gbs + gl,
                                          nullptr, hh);
    ln_elu_h<<<BB / 4, 256, 0, stream>>>(hh, xh);
    // layer 2 (no LN, fp32 out)
    gemm_layer<0><<<gg, 128, 0, stream>>>(xh, Wh + 2 * wsl, pWs + 2 * pl,
                                          pbs + 2 * pl, bs + 2 * bsl,
                                          gWs + 2 * gl, gbs + 2 * gl,
                                          out, nullptr);
}

// Round 13
// 351.952 us; speedup vs baseline: 1.7553x; 1.0264x over previous
//
#include <hip/hip_runtime.h>
#include <math.h>

// Problem constants (B=10240, D=512, M=8, L=3)
#define BB   10240
#define DD   512
#define MM   8

typedef _Float16 h8 __attribute__((ext_vector_type(8)));
typedef float    f4 __attribute__((ext_vector_type(4)));

// async global->LDS DMA, 16 B per lane; LDS dst = wave-uniform base + lane*16
__device__ __forceinline__ void gload16(const void* g, void* l) {
    __builtin_amdgcn_global_load_lds(
        (__attribute__((address_space(1))) void*)(g),
        (__attribute__((address_space(3))) void*)(l), 16, 0, 0);
}

// ------------- merged fp32 -> fp16 convert (Ws then x, one launch) ---------
#define N8_WS 786432   // 3*8*512*512/8
#define N8_X  655360   // B*512/8
__global__ void __launch_bounds__(256) cvt_all(const float* __restrict__ Ws,
                                               const float* __restrict__ x,
                                               _Float16* __restrict__ Wh,
                                               _Float16* __restrict__ xh) {
    int i = blockIdx.x * 256 + threadIdx.x;
    const float* s; _Float16* d; int idx;
    if (i < N8_WS)            { s = Ws; d = Wh; idx = i; }
    else if (i < N8_WS + N8_X){ s = x;  d = xh; idx = i - N8_WS; }
    else return;
    const float4* sp = (const float4*)s + (size_t)idx * 2;
    float4 a = sp[0], b = sp[1];
    h8 o = { (_Float16)a.x, (_Float16)a.y, (_Float16)a.z, (_Float16)a.w,
             (_Float16)b.x, (_Float16)b.y, (_Float16)b.z, (_Float16)b.w };
    *(h8*)(d + (size_t)idx * 8) = o;
}

// ---------------- fused layer GEMM ----------------
// C[b,i] = gW[b,i] * sum_m pW[b,m] sum_j W[m,i,j] x[b,j]  +  gb[b,i]*sum_m pb[b,m]*bs[m,i]
//
// R12 -> R13: occupancy + intra-wave pipeline.  R12 evidence: ~1000 cyc/step
// vs ~350 issue floor at 1.25 waves/SIMD — pure latency exposure.  Changes:
//  (1) BM 128->64: grid (8,160)=1280 blocks, 4 resident/CU (40 KB LDS)
//      -> 2 waves/SIMD (2x TLP).  W-staging bytes double (L2-side, proven
//      free in R10).
//  (2) wfr 1-step prefetch, 4-slot ring (lead 3): step T reads W frags for
//      T+1 into the alternate register set -> no per-step ds_read->MFMA
//      latency chain.  vmcnt retires through stage(T+1):
//      steady N=[8,8,12,12,12,8,8,8] (A retired at mi5), tail 8x5,4,0,0.
//  A tile 64x64 (8 KB) block-shared, STA at mi2, AFR at mi0; 2 barriers/jc.
template <int HALF_OUT>
__global__ void __launch_bounds__(128, 3) gemm_layer(
    const _Float16* __restrict__ xh,   // (B,512) fp16
    const _Float16* __restrict__ Wh,   // (8,512,512) fp16
    const float*  __restrict__ pW,     // (B,8)
    const float*  __restrict__ pb,     // (B,8)
    const float*  __restrict__ bsv,    // (8,512)
    const float*  __restrict__ gW,     // (B,512)
    const float*  __restrict__ gb,     // (B,512)
    float* __restrict__ outf,          // (B,512) fp32 (final layer)
    _Float16* __restrict__ outh)       // (B,512) fp16 (hidden layers)
{
    // W: wave-private ring, 2 waves x 4 slots x (32 rows x 64 cols) = 32 KB
    __shared__ __align__(16) _Float16 Wl[2][4][32 * 64];
    // A: block-shared single buffer, 64 rows x 64 cols = 8 KB
    __shared__ __align__(16) _Float16 Ab[64 * 64];

    const int tid  = threadIdx.x;
    const int lane = tid & 63;
    const int w    = tid >> 6;           // wave 0/1 -> W cols [w*32, w*32+32)
    const int ln16 = lane & 15, quad = lane >> 4;
    const int bn0  = blockIdx.x * 64;
    const int bm0  = blockIdx.y * 64;

    // per-lane pW for 4 A-row groups (64 rows), all 8 m, as fp16
    _Float16 pwh[4][8];
    #pragma unroll
    for (int mt = 0; mt < 4; ++mt) {
        const float* pp = pW + (size_t)(bm0 + mt * 16 + ln16) * MM;
        float4 p0 = *(const float4*)pp;
        float4 p1 = *(const float4*)(pp + 4);
        pwh[mt][0] = (_Float16)p0.x; pwh[mt][1] = (_Float16)p0.y;
        pwh[mt][2] = (_Float16)p0.z; pwh[mt][3] = (_Float16)p0.w;
        pwh[mt][4] = (_Float16)p1.x; pwh[mt][5] = (_Float16)p1.y;
        pwh[mt][6] = (_Float16)p1.z; pwh[mt][7] = (_Float16)p1.w;
    }

    f4 acc[4][2] = {};
    h8 afr[2][4];      // A fragments for current jc
    h8 wfr[2][2][2];   // [set=T&1][ks][nt] W fragments, double-buffered

// stage wave's 32x64 W half-tile (basis M_, k-chunk JC_) into ring slot S_
#define STW(S_, M_, JC_) do {                                                  \
    _Pragma("unroll")                                                          \
    for (int c = 0; c < 4; ++c) {                                              \
        int rit     = c * 8 + (lane >> 3);                                     \
        int logical = (lane & 7) ^ (lane >> 3);                                \
        const _Float16* gp = Wh + (size_t)(M_) * (DD * DD)                     \
                               + (size_t)(bn0 + w * 32 + rit) * DD             \
                               + (JC_) * 64 + logical * 8;                     \
        gload16(gp, &Wl[w][S_][c * 512]);                                      \
    }                                                                          \
} while (0)

// stage A(jc) tile (64x64) into Ab; wave w does rows w*32..+32 (4x1KB)
#define STA(JC_) do {                                                          \
    _Pragma("unroll")                                                          \
    for (int c = 0; c < 4; ++c) {                                              \
        int rit     = w * 32 + c * 8 + (lane >> 3);                            \
        int logical = (lane & 7) ^ (lane >> 3);                                \
        const _Float16* gp = xh + (size_t)(bm0 + rit) * DD                     \
                                + (JC_) * 64 + logical * 8;                    \
        gload16(gp, &Ab[(w * 32 + c * 8) * 64]);                               \
    }                                                                          \
} while (0)

// read 8 A fragments for this jc from Ab (swizzled ds_read_b128)
#define AFR() do {                                                             \
    _Pragma("unroll")                                                          \
    for (int _ks = 0; _ks < 2; ++_ks)                                          \
        _Pragma("unroll")                                                      \
        for (int _mt = 0; _mt < 4; ++_mt) {                                    \
            int _phys = (_ks * 4 + quad) ^ (ln16 & 7);                         \
            afr[_ks][_mt] = *(const h8*)&Ab[(_mt * 16 + ln16) * 64             \
                                            + _phys * 8];                      \
        }                                                                      \
} while (0)

// one step T_: STW(T+3), [STA], vmcnt(N) retiring through stage(T+1),
// [AFR], prefetch wfr(T+1) into set (T+1)&1, 16 MFMA with set T&1,
// [B2 end of mi0], [B1 end of mi7].
#define GS(T_, N_, AF_, SA_, B1_, B2_) do {                                    \
    if ((T_) + 3 <= 63) STW((((T_) + 3) & 3), (((T_) + 3) & 7),                \
                            (((T_) + 3) >> 3));                                \
    if (SA_) STA(((T_) >> 3) + 1);                                             \
    asm volatile("s_waitcnt vmcnt(%0)" :: "i"(N_) : "memory");                 \
    __builtin_amdgcn_sched_barrier(0);                                         \
    if (AF_) AFR();                                                            \
    if ((T_) < 63) {                                                           \
        _Pragma("unroll")                                                      \
        for (int ks = 0; ks < 2; ++ks)                                         \
            _Pragma("unroll")                                                  \
            for (int nt = 0; nt < 2; ++nt) {                                   \
                int row  = nt * 16 + ln16;                                     \
                int phys = (ks * 4 + quad) ^ (ln16 & 7);                       \
                wfr[((T_) + 1) & 1][ks][nt] =                                  \
                    *(const h8*)&Wl[w][((T_) + 1) & 3][row * 64 + phys * 8];   \
            }                                                                  \
    }                                                                          \
    _Pragma("unroll")                                                          \
    for (int ks = 0; ks < 2; ++ks)                                             \
        _Pragma("unroll")                                                      \
        for (int mt = 0; mt < 4; ++mt) {                                       \
            h8 as = afr[ks][mt] * pwh[mt][(T_) & 7];  /* v_pk_mul_f16 x4 */    \
            acc[mt][0] = __builtin_amdgcn_mfma_f32_16x16x32_f16(               \
                as, wfr[(T_) & 1][ks][0], acc[mt][0], 0, 0, 0);                \
            acc[mt][1] = __builtin_amdgcn_mfma_f32_16x16x32_f16(               \
                as, wfr[(T_) & 1][ks][1], acc[mt][1], 0, 0, 0);                \
        }                                                                      \
    if (B2_) { asm volatile("s_waitcnt lgkmcnt(0)" ::: "memory");              \
               __builtin_amdgcn_s_barrier();                                   \
               asm volatile("" ::: "memory"); }                                \
    if (B1_) { __builtin_amdgcn_s_barrier();                                   \
               asm volatile("" ::: "memory"); }                                \
} while (0)

    // prologue: A(0), stages 0,1,2; retire A+stage(0); seed wfr set 0; barrier.
    STA(0);
    STW(0, 0, 0);
    STW(1, 1, 0);
    STW(2, 2, 0);
    asm volatile("s_waitcnt vmcnt(8)" ::: "memory");
    __builtin_amdgcn_sched_barrier(0);
    #pragma unroll
    for (int ks = 0; ks < 2; ++ks)
        #pragma unroll
        for (int nt = 0; nt < 2; ++nt) {
            int row  = nt * 16 + ln16;
            int phys = (ks * 4 + quad) ^ (ln16 & 7);
            wfr[0][ks][nt] = *(const h8*)&Wl[w][0][row * 64 + phys * 8];
        }
    __builtin_amdgcn_s_barrier();
    asm volatile("" ::: "memory");

    //   T    N  AF SA B1 B2          (steady: N=[8,8,12,12,12,8,8,8])
    GS(  0,  8, 1, 0, 0, 1);
    GS(  1,  8, 0, 0, 0, 0);
    GS(  2, 12, 0, 1, 0, 0);
    GS(  3, 12, 0, 0, 0, 0);
    GS(  4, 12, 0, 0, 0, 0);
    GS(  5,  8, 0, 0, 0, 0);
    GS(  6,  8, 0, 0, 0, 0);
    GS(  7,  8, 0, 0, 1, 0);
    GS(  8,  8, 1, 0, 0, 1);
    GS(  9,  8, 0, 0, 0, 0);
    GS( 10, 12, 0, 1, 0, 0);
    GS( 11, 12, 0, 0, 0, 0);
    GS( 12, 12, 0, 0, 0, 0);
    GS( 13,  8, 0, 0, 0, 0);
    GS( 14,  8, 0, 0, 0, 0);
    GS( 15,  8, 0, 0, 1, 0);
    GS( 16,  8, 1, 0, 0, 1);
    GS( 17,  8, 0, 0, 0, 0);
    GS( 18, 12, 0, 1, 0, 0);
    GS( 19, 12, 0, 0, 0, 0);
    GS( 20, 12, 0, 0, 0, 0);
    GS( 21,  8, 0, 0, 0, 0);
    GS( 22,  8, 0, 0, 0, 0);
    GS( 23,  8, 0, 0, 1, 0);
    GS( 24,  8, 1, 0, 0, 1);
    GS( 25,  8, 0, 0, 0, 0);
    GS( 26, 12, 0, 1, 0, 0);
    GS( 27, 12, 0, 0, 0, 0);
    GS( 28, 12, 0, 0, 0, 0);
    GS( 29,  8, 0, 0, 0, 0);
    GS( 30,  8, 0, 0, 0, 0);
    GS( 31,  8, 0, 0, 1, 0);
    GS( 32,  8, 1, 0, 0, 1);
    GS( 33,  8, 0, 0, 0, 0);
    GS( 34, 12, 0, 1, 0, 0);
    GS( 35, 12, 0, 0, 0, 0);
    GS( 36, 12, 0, 0, 0, 0);
    GS( 37,  8, 0, 0, 0, 0);
    GS( 38,  8, 0, 0, 0, 0);
    GS( 39,  8, 0, 0, 1, 0);
    GS( 40,  8, 1, 0, 0, 1);
    GS( 41,  8, 0, 0, 0, 0);
    GS( 42, 12, 0, 1, 0, 0);
    GS( 43, 12, 0, 0, 0, 0);
    GS( 44, 12, 0, 0, 0, 0);
    GS( 45,  8, 0, 0, 0, 0);
    GS( 46,  8, 0, 0, 0, 0);
    GS( 47,  8, 0, 0, 1, 0);
    GS( 48,  8, 1, 0, 0, 1);
    GS( 49,  8, 0, 0, 0, 0);
    GS( 50, 12, 0, 1, 0, 0);   // stages A(7)
    GS( 51, 12, 0, 0, 0, 0);
    GS( 52, 12, 0, 0, 0, 0);
    GS( 53,  8, 0, 0, 0, 0);
    GS( 54,  8, 0, 0, 0, 0);
    GS( 55,  8, 0, 0, 1, 0);
    GS( 56,  8, 1, 0, 0, 0);   // jc=7: no STA, no barriers
    GS( 57,  8, 0, 0, 0, 0);
    GS( 58,  8, 0, 0, 0, 0);
    GS( 59,  8, 0, 0, 0, 0);
    GS( 60,  8, 0, 0, 0, 0);
    GS( 61,  4, 0, 0, 0, 0);
    GS( 62,  0, 0, 0, 0, 0);
    GS( 63,  0, 0, 0, 0, 0);

#undef GS
#undef AFR
#undef STA
#undef STW

    // ---- epilogue: out = gW*acc + gb*(sum_m pb*bs) ----
    const int i0 = bn0 + w * 32 + ln16;
    const int i1 = i0 + 16;
    float bs0[8], bs1[8];
    #pragma unroll
    for (int m2 = 0; m2 < 8; ++m2) {
        bs0[m2] = bsv[m2 * DD + i0];
        bs1[m2] = bsv[m2 * DD + i1];
    }
    #pragma unroll
    for (int mt = 0; mt < 4; ++mt) {
        #pragma unroll
        for (int r = 0; r < 4; ++r) {
            int b = bm0 + mt * 16 + quad * 4 + r;
            float4 p0 = *(const float4*)(pb + (size_t)b * MM);
            float4 p1 = *(const float4*)(pb + (size_t)b * MM + 4);
            float bias0 = p0.x*bs0[0] + p0.y*bs0[1] + p0.z*bs0[2] + p0.w*bs0[3]
                        + p1.x*bs0[4] + p1.y*bs0[5] + p1.z*bs0[6] + p1.w*bs0[7];
            float bias1 = p0.x*bs1[0] + p0.y*bs1[1] + p0.z*bs1[2] + p0.w*bs1[3]
                        + p1.x*bs1[4] + p1.y*bs1[5] + p1.z*bs1[6] + p1.w*bs1[7];
            float v0 = gW[(size_t)b * DD + i0] * acc[mt][0][r] + gb[(size_t)b * DD + i0] * bias0;
            float v1 = gW[(size_t)b * DD + i1] * acc[mt][1][r] + gb[(size_t)b * DD + i1] * bias1;
            if (HALF_OUT) {
                outh[(size_t)b * DD + i0] = (_Float16)v0;
                outh[(size_t)b * DD + i1] = (_Float16)v1;
            } else {
                outf[(size_t)b * DD + i0] = v0;
                outf[(size_t)b * DD + i1] = v1;
            }
        }
    }
}

// ---------------- LayerNorm (no affine) + ELU, fp16 in/out ----------------
__global__ void __launch_bounds__(256) ln_elu_h(const _Float16* __restrict__ h,
                                                _Float16* __restrict__ xo) {
    const int w    = threadIdx.x >> 6;
    const int lane = threadIdx.x & 63;
    const int row  = blockIdx.x * 4 + w;
    h8 v = *(const h8*)(h + (size_t)row * DD + lane * 8);
    float f[8], s = 0.f, q = 0.f;
    #pragma unroll
    for (int i = 0; i < 8; ++i) { f[i] = (float)v[i]; s += f[i]; q += f[i] * f[i]; }
    #pragma unroll
    for (int off = 1; off < 64; off <<= 1) {
        s += __shfl_xor(s, off);
        q += __shfl_xor(q, off);
    }
    float mu   = s * (1.0f / 512.0f);
    float var  = q * (1.0f / 512.0f) - mu * mu;
    float rstd = rsqrtf(var + 1e-5f);
    h8 o;
    #pragma unroll
    for (int i = 0; i < 8; ++i) {
        float t = (f[i] - mu) * rstd;
        t = t > 0.0f ? t : expm1f(t);
        o[i] = (_Float16)t;
    }
    *(h8*)(xo + (size_t)row * DD + lane * 8) = o;
}

extern "C" void kernel_launch(void* const* d_in, const int* in_sizes, int n_in,
                              void* d_out, int out_size, void* d_ws, size_t ws_size,
                              hipStream_t stream) {
    const float* x   = (const float*)d_in[0];   // (B,512)
    const float* Ws  = (const float*)d_in[1];   // (3,8,512,512)
    const float* bs  = (const float*)d_in[2];   // (3,8,512)
    const float* pWs = (const float*)d_in[3];   // (3,B,8)
    const float* pbs = (const float*)d_in[4];   // (3,B,8)
    const float* gWs = (const float*)d_in[5];   // (3,B,512,1)
    const float* gbs = (const float*)d_in[6];   // (3,B,512)
    float* out = (float*)d_out;

    // workspace: Wh 12.58 MB + xh 10.49 MB + hh 10.49 MB = 32 MiB exactly
    _Float16* Wh = (_Float16*)d_ws;
    _Float16* xh = Wh + (size_t)3 * MM * DD * DD;
    _Float16* hh = xh + (size_t)BB * DD;

    const int wsl = MM * DD * DD;        // per-layer W elems
    const int bsl = MM * DD;
    const int pl  = BB * MM;
    const int gl  = BB * DD;

    cvt_all<<<(N8_WS + N8_X) / 256, 256, 0, stream>>>(Ws, x, Wh, xh);

    dim3 gg(DD / 64, BB / 64);           // (8, 160): column-slice x -> XCD x

    // layer 0
    gemm_layer<1><<<gg, 128, 0, stream>>>(xh, Wh, pWs, pbs, bs, gWs, gbs,
                                          nullptr, hh);
    ln_elu_h<<<BB / 4, 256, 0, stream>>>(hh, xh);
    // layer 1
    gemm_layer<1><<<gg, 128, 0, stream>>>(xh, Wh + wsl, pWs + pl, pbs + pl,
                                          bs + bsl, gWs + gl, gbs + gl,
                                          nullptr, hh);
    ln_elu_h<<<BB / 4, 256, 0, stream>>>(hh, xh);
    // layer 2 (no LN, fp32 out)
    gemm_layer<0><<<gg, 128, 0, stream>>>(xh, Wh + 2 * wsl, pWs + 2 * pl,
                                          pbs + 2 * pl, bs + 2 * bsl,
                                          gWs + 2 * gl, gbs + 2 * gl,
                                          out, nullptr);
}